// Round 3
// baseline (4713.863 us; speedup 1.0000x reference)
//
#include <hip/hip_runtime.h>
#include <hip/hip_bf16.h>
#include <math.h>

// Problem constants (fixed by the reference)
#define BB    8
#define LL    2048
#define DMOD  1024
#define DI    2048
#define NST   16
#define MR    (BB*LL)   // 16384 rows

typedef unsigned short bf16_t;

__device__ __forceinline__ float b2f(bf16_t u) {
  return __uint_as_float(((unsigned int)u) << 16);
}
__device__ __forceinline__ bf16_t f2b(float f) {
  unsigned int u = __float_as_uint(f);
  unsigned int r = (u + 0x7FFFu + ((u >> 16) & 1u)) >> 16;  // RNE
  return (bf16_t)r;
}

// vector load/store of 4 elements as fp32, overloaded on storage type
__device__ __forceinline__ float4 load4(const float* p) { return *(const float4*)p; }
__device__ __forceinline__ float4 load4(const bf16_t* p) {
  ushort4 u = *(const ushort4*)p;
  return make_float4(b2f(u.x), b2f(u.y), b2f(u.z), b2f(u.w));
}
__device__ __forceinline__ void store4(float* p, float4 v) { *(float4*)p = v; }
__device__ __forceinline__ void store4(bf16_t* p, float4 v) {
  ushort4 u; u.x = f2b(v.x); u.y = f2b(v.y); u.z = f2b(v.z); u.w = f2b(v.w);
  *(ushort4*)p = u;
}

// ---------------------------------------------------------------------------
// GEMM NT, fp32 accumulate: C[M,N] = A[M,K] * B[N,K]^T (row-major, K contig).
// 128x128 tile, BK=8, 256 threads, 8x8 microtile per thread.
// ---------------------------------------------------------------------------
template <typename TA, typename TB, typename TC>
__global__ __launch_bounds__(256) void gemm_nt(
    const TA* __restrict__ A, const TB* __restrict__ B,
    TC* __restrict__ C, int M, int N, int K)
{
  __shared__ float As[8][128];
  __shared__ float Bs[8][128];
  const int tid = threadIdx.x;
  const int m0 = blockIdx.y * 128;
  const int n0 = blockIdx.x * 128;
  const int sm = tid >> 1;          // staging row within tile (0..127)
  const int sk = (tid & 1) * 4;     // staging k offset (0 or 4)
  const int tx = tid & 15;          // n sub-tile
  const int ty = tid >> 4;          // m sub-tile
  const TA* Ag = A + (size_t)(m0 + sm) * K + sk;
  const TB* Bg = B + (size_t)(n0 + sm) * K + sk;

  float acc[8][8];
#pragma unroll
  for (int i = 0; i < 8; ++i)
#pragma unroll
    for (int j = 0; j < 8; ++j) acc[i][j] = 0.f;

  for (int k0 = 0; k0 < K; k0 += 8) {
    float4 av = load4(Ag + k0);
    float4 bv = load4(Bg + k0);
    __syncthreads();   // previous iteration's readers done
    As[sk+0][sm] = av.x; As[sk+1][sm] = av.y; As[sk+2][sm] = av.z; As[sk+3][sm] = av.w;
    Bs[sk+0][sm] = bv.x; Bs[sk+1][sm] = bv.y; Bs[sk+2][sm] = bv.z; Bs[sk+3][sm] = bv.w;
    __syncthreads();
#pragma unroll
    for (int kk = 0; kk < 8; ++kk) {
      float4 a0 = *(const float4*)&As[kk][ty*4];
      float4 a1 = *(const float4*)&As[kk][ty*4 + 64];
      float4 b0 = *(const float4*)&Bs[kk][tx*4];
      float4 b1 = *(const float4*)&Bs[kk][tx*4 + 64];
      float ar[8] = {a0.x,a0.y,a0.z,a0.w,a1.x,a1.y,a1.z,a1.w};
      float br[8] = {b0.x,b0.y,b0.z,b0.w,b1.x,b1.y,b1.z,b1.w};
#pragma unroll
      for (int i = 0; i < 8; ++i)
#pragma unroll
        for (int j = 0; j < 8; ++j)
          acc[i][j] += ar[i] * br[j];
    }
  }

#pragma unroll
  for (int ih = 0; ih < 2; ++ih)
#pragma unroll
    for (int i = 0; i < 4; ++i) {
      int ri = ih*4 + i;
      TC* cp = C + (size_t)(m0 + ih*64 + ty*4 + i) * N + n0;
      store4(cp + tx*4,      make_float4(acc[ri][0], acc[ri][1], acc[ri][2], acc[ri][3]));
      store4(cp + 64 + tx*4, make_float4(acc[ri][4], acc[ri][5], acc[ri][6], acc[ri][7]));
    }
}

// ---------------------------------------------------------------------------
// Causal depthwise conv1d (k=4) + bias + SiLU.
// xz: bf16 [B*L, 4096] (xi = first 2048 cols). xs out: bf16 [B*L, 2048].
// Weights/bias fp32. One thread = 4 consecutive channels at one (b,l).
// ---------------------------------------------------------------------------
__global__ __launch_bounds__(256) void conv_silu(
    const bf16_t* __restrict__ xz, const float* __restrict__ cw,
    const float* __restrict__ cb, bf16_t* __restrict__ xs)
{
  int idx = blockIdx.x * 256 + threadIdx.x;   // 8*2048*512 = 2^22 threads
  int d4 = idx & 511;
  int l  = (idx >> 9) & 2047;
  int b  = idx >> 20;
  int d  = d4 * 4;

  float wch[4][4];
#pragma unroll
  for (int c = 0; c < 4; ++c)
#pragma unroll
    for (int k = 0; k < 4; ++k) wch[c][k] = cw[(d + c) * 4 + k];

  float acc0 = cb[d+0], acc1 = cb[d+1], acc2 = cb[d+2], acc3 = cb[d+3];
  size_t rowbase = ((size_t)b * LL + l) * 4096 + d;
#pragma unroll
  for (int k = 0; k < 4; ++k) {
    int lp = l - 3 + k;
    if (lp >= 0) {
      float4 xv = load4(xz + rowbase - (size_t)(3 - k) * 4096);
      acc0 += xv.x * wch[0][k];
      acc1 += xv.y * wch[1][k];
      acc2 += xv.z * wch[2][k];
      acc3 += xv.w * wch[3][k];
    }
  }
  float4 o;
  o.x = acc0 / (1.f + __expf(-acc0));
  o.y = acc1 / (1.f + __expf(-acc1));
  o.z = acc2 / (1.f + __expf(-acc2));
  o.w = acc3 / (1.f + __expf(-acc3));
  store4(xs + ((size_t)b * LL + l) * (size_t)DI + d, o);
}

// ---------------------------------------------------------------------------
// x_dbl[M,33] = xs[M,2048](bf16) @ W_x[33,2048](fp32)^T -> fp32.
// Block = 64 rows, 256 threads; thread (row=tid&63, jg=tid>>6) does cols
// jg, jg+4, ...
// ---------------------------------------------------------------------------
__global__ __launch_bounds__(256) void xdbl_gemm(
    const bf16_t* __restrict__ xs, const float* __restrict__ W_x,
    float* __restrict__ xdbl)
{
  int row = blockIdx.x * 64 + (threadIdx.x & 63);
  int jg  = threadIdx.x >> 6;          // 0..3 (wave-uniform)
  const bf16_t* a = xs + (size_t)row * DI;
  float acc[9];
#pragma unroll
  for (int t = 0; t < 9; ++t) acc[t] = 0.f;

  for (int d = 0; d < DI; d += 4) {
    float4 av = load4(a + d);
#pragma unroll
    for (int t = 0; t < 9; ++t) {
      int j = jg + t * 4;
      if (j < 33) {
        float4 wv = load4(W_x + (size_t)j * DI + d);
        acc[t] += av.x*wv.x + av.y*wv.y + av.z*wv.z + av.w*wv.w;
      }
    }
  }
#pragma unroll
  for (int t = 0; t < 9; ++t) {
    int j = jg + t * 4;
    if (j < 33) xdbl[(size_t)row * 33 + j] = acc[t];
  }
}

// ---------------------------------------------------------------------------
// Selective scan + D*xs + SiLU(z) gating, fused.  One thread per (b, d).
// Grid: 64 blocks (8 b x 8 d-groups) x 256 threads.
// Writes gated output (bf16) in-place over xs.
// ---------------------------------------------------------------------------
__global__ __launch_bounds__(256) void ssm_scan(
    const float*  __restrict__ xdbl,   // [B*L, 33] fp32
    const bf16_t* __restrict__ xz,     // [B*L, 4096]; z at col 2048+d
    bf16_t*       __restrict__ xs,     // [B*L, 2048] in: conv+silu, out: gated y
    const float*  __restrict__ W_dt,   // [2048]
    const float*  __restrict__ b_dt,   // [2048]
    const float*  __restrict__ A_log,  // [2048,16]
    const float*  __restrict__ Dp)     // [2048]
{
  const int b  = blockIdx.x >> 3;
  const int dg = blockIdx.x & 7;
  const int d  = dg * 256 + threadIdx.x;

  float A[NST], h[NST];
#pragma unroll
  for (int n = 0; n < NST; ++n) {
    A[n] = -__expf(A_log[(size_t)d * NST + n]);
    h[n] = 0.f;
  }
  const float wdt = W_dt[d];
  const float bdt = b_dt[d];
  const float Dd  = Dp[d];

  __shared__ float sh[2][33];
  const size_t base = (size_t)b * LL;

  if (threadIdx.x < 33) sh[0][threadIdx.x] = xdbl[base * 33 + threadIdx.x];
  float xv = b2f(xs[base * DI + d]);
  float zv = b2f(xz[base * 4096 + DI + d]);
  __syncthreads();

  for (int l = 0; l < LL; ++l) {
    // software prefetch for step l+1 (issued before the exp chain)
    float xv_n = 0.f, zv_n = 0.f, dbl_n = 0.f;
    if (l + 1 < LL) {
      size_t r = base + l + 1;
      xv_n = b2f(xs[r * DI + d]);
      zv_n = b2f(xz[r * 4096 + DI + d]);
      if (threadIdx.x < 33) dbl_n = xdbl[r * 33 + threadIdx.x];
    }
    const int cur = l & 1;
    float dtr  = sh[cur][0];
    float xarg = dtr * wdt + bdt;
    float dt   = (xarg > 20.f) ? xarg : log1pf(__expf(xarg));
    float dtx  = dt * xv;
    float y    = 0.f;
#pragma unroll
    for (int n = 0; n < NST; ++n) {
      float Bv = sh[cur][1 + n];
      float Cv = sh[cur][17 + n];
      h[n] = __expf(dt * A[n]) * h[n] + dtx * Bv;
      y   += h[n] * Cv;
    }
    y += Dd * xv;
    float sz = zv / (1.f + __expf(-zv));
    xs[(base + l) * DI + d] = f2b(y * sz);

    if (threadIdx.x < 33) sh[cur ^ 1][threadIdx.x] = dbl_n;
    __syncthreads();
    xv = xv_n; zv = zv_n;
  }
}

// ---------------------------------------------------------------------------
extern "C" void kernel_launch(void* const* d_in, const int* in_sizes, int n_in,
                              void* d_out, int out_size, void* d_ws, size_t ws_size,
                              hipStream_t stream)
{
  const float* x     = (const float*)d_in[0];
  const float* W_in  = (const float*)d_in[1];
  const float* cw    = (const float*)d_in[2];
  const float* cb    = (const float*)d_in[3];
  const float* W_x   = (const float*)d_in[4];
  const float* W_dt  = (const float*)d_in[5];
  const float* b_dt  = (const float*)d_in[6];
  const float* A_log = (const float*)d_in[7];
  const float* Dp    = (const float*)d_in[8];
  const float* W_out = (const float*)d_in[9];
  float* out = (float*)d_out;

  // Workspace: xz bf16 [16384,4096] (128 MiB) | xs bf16 [16384,2048] (64 MiB)
  //            | xdbl f32 [16384,33] (~2 MiB).  Total ~194 MiB (fit verified R2).
  bf16_t* xz = (bf16_t*)d_ws;
  bf16_t* xs = xz + (size_t)MR * 4096;
  float* xdbl = (float*)(xs + (size_t)MR * DI);

  // 1) xz = x @ W_in^T        (M=16384, N=4096, K=1024)  f32*f32 -> bf16
  gemm_nt<float, float, bf16_t>
      <<<dim3(4096/128, MR/128), 256, 0, stream>>>(x, W_in, xz, MR, 4096, DMOD);
  // 2) causal depthwise conv + bias + SiLU -> xs (bf16)
  conv_silu<<<(BB*LL*512)/256, 256, 0, stream>>>(xz, cw, cb, xs);
  // 3) x_dbl = xs @ W_x^T     (M=16384, N=33, K=2048)  bf16*f32 -> f32
  xdbl_gemm<<<MR/64, 256, 0, stream>>>(xs, W_x, xdbl);
  // 4) selective scan + D*xs + SiLU(z) gating (in-place into xs, bf16)
  ssm_scan<<<64, 256, 0, stream>>>(xdbl, xz, xs, W_dt, b_dt, A_log, Dp);
  // 5) out = gated @ W_out^T  (M=16384, N=1024, K=2048)  bf16*f32 -> f32
  gemm_nt<bf16_t, float, float>
      <<<dim3(1024/128, MR/128), 256, 0, stream>>>(xs, W_out, out, MR, 1024, DI);
}

// Round 4
// 1368.822 us; speedup vs baseline: 3.4437x; 3.4437x over previous
//
#include <hip/hip_runtime.h>
#include <math.h>

// Problem constants (fixed by the reference)
#define BB    8
#define LL    2048
#define DMOD  1024
#define DI    2048
#define NST   16
#define MR    (BB*LL)   // 16384 rows
// scan chunking
#define NCH   8
#define CLEN  256       // NCH*CLEN == LL
#define SUB   64        // xdbl LDS staging granularity

typedef unsigned short bf16_t;
typedef __attribute__((ext_vector_type(8))) __bf16 bf16x8;
typedef __attribute__((ext_vector_type(4))) float  f32x4;

__device__ __forceinline__ float b2f(bf16_t u) {
  return __uint_as_float(((unsigned int)u) << 16);
}
__device__ __forceinline__ bf16_t f2b(float f) {
  unsigned int u = __float_as_uint(f);
  unsigned int r = (u + 0x7FFFu + ((u >> 16) & 1u)) >> 16;  // RNE
  return (bf16_t)r;
}

__device__ __forceinline__ void cstore(float* p, float v)  { *p = v; }
__device__ __forceinline__ void cstore(bf16_t* p, float v) { *p = f2b(v); }

// async global->LDS, 16B per lane; LDS dest = wave-uniform base + lane*16
__device__ __forceinline__ void gld16(const bf16_t* g, bf16_t* l) {
  __builtin_amdgcn_global_load_lds(
      (const __attribute__((address_space(1))) unsigned int*)g,
      (__attribute__((address_space(3))) unsigned int*)l, 16, 0, 0);
}

// ---------------------------------------------------------------------------
// fp32 -> bf16 convert (vectorized x4)
// ---------------------------------------------------------------------------
__global__ __launch_bounds__(256) void cvt_bf16(
    const float* __restrict__ in, bf16_t* __restrict__ out, int n4)
{
  int i = blockIdx.x * 256 + threadIdx.x;
  if (i >= n4) return;
  float4 v = ((const float4*)in)[i];
  ushort4 u;
  u.x = f2b(v.x); u.y = f2b(v.y); u.z = f2b(v.z); u.w = f2b(v.w);
  ((ushort4*)out)[i] = u;
}

// ---------------------------------------------------------------------------
// MFMA GEMM NT: C[M,N] = A[M,K] * B[N,K]^T, bf16 inputs, fp32 acc.
// m97 structure: 128x128 tile, BK=32, 256 thr (4 waves), 4x4 16x16x32 per wave.
// grid = dim3(N/128, M/128).  M,N,K multiples of 128/128/32.
// ---------------------------------------------------------------------------
template <typename TC>
__global__ __launch_bounds__(256) void mgemm_nt(
    const bf16_t* __restrict__ A, const bf16_t* __restrict__ B,
    TC* __restrict__ C, int N, int K)
{
  __shared__ __align__(16) bf16_t As[128 * 32];
  __shared__ __align__(16) bf16_t Bs[128 * 32];
  const int tid  = threadIdx.x;
  const int wave = tid >> 6;
  const int lane = tid & 63;
  const int m0 = blockIdx.y * 128;
  const int n0 = blockIdx.x * 128;
  const int wm = (wave >> 1) * 64;
  const int wn = (wave & 1) * 64;
  const int fr = lane & 15;
  const int quad = lane >> 4;

  // staging: per wave 2 insts per tile; inst q covers rows wave*32+q*16..+16
  const int srow = wave * 32 + (lane >> 2);
  const int scol = (lane & 3) * 8;                 // elements (8 bf16 = 16 B)
  const bf16_t* Ag0 = A + (size_t)(m0 + srow) * K + scol;
  const bf16_t* Ag1 = Ag0 + (size_t)16 * K;
  const bf16_t* Bg0 = B + (size_t)(n0 + srow) * K + scol;
  const bf16_t* Bg1 = Bg0 + (size_t)16 * K;
  bf16_t* lA0 = As + (wave * 32) * 32;
  bf16_t* lA1 = As + (wave * 32 + 16) * 32;
  bf16_t* lB0 = Bs + (wave * 32) * 32;
  bf16_t* lB1 = Bs + (wave * 32 + 16) * 32;

  f32x4 acc[4][4];
#pragma unroll
  for (int i = 0; i < 4; ++i)
#pragma unroll
    for (int j = 0; j < 4; ++j) acc[i][j] = (f32x4){0.f, 0.f, 0.f, 0.f};

  for (int k0 = 0; k0 < K; k0 += 32) {
    __syncthreads();                 // prior iteration's ds_reads complete
    gld16(Ag0 + k0, lA0);
    gld16(Ag1 + k0, lA1);
    gld16(Bg0 + k0, lB0);
    gld16(Bg1 + k0, lB1);
    __syncthreads();                 // drains vmcnt -> LDS tiles valid

    bf16x8 a[4], b[4];
#pragma unroll
    for (int i = 0; i < 4; ++i)
      a[i] = *(const bf16x8*)&As[(wm + i * 16 + fr) * 32 + quad * 8];
#pragma unroll
    for (int j = 0; j < 4; ++j)
      b[j] = *(const bf16x8*)&Bs[(wn + j * 16 + fr) * 32 + quad * 8];
#pragma unroll
    for (int i = 0; i < 4; ++i)
#pragma unroll
      for (int j = 0; j < 4; ++j)
        acc[i][j] = __builtin_amdgcn_mfma_f32_16x16x32_bf16(a[i], b[j], acc[i][j], 0, 0, 0);
  }

  // epilogue: D col = lane&15, row = quad*4 + r  (verified m89/m91)
#pragma unroll
  for (int i = 0; i < 4; ++i)
#pragma unroll
    for (int j = 0; j < 4; ++j) {
#pragma unroll
      for (int r = 0; r < 4; ++r) {
        int grow = m0 + wm + i * 16 + quad * 4 + r;
        int gcol = n0 + wn + j * 16 + fr;
        cstore(&C[(size_t)grow * N + gcol], acc[i][j][r]);
      }
    }
}

// ---------------------------------------------------------------------------
// Causal depthwise conv1d (k=4) + bias + SiLU.  bf16 xz -> bf16 xs.
// ---------------------------------------------------------------------------
__global__ __launch_bounds__(256) void conv_silu(
    const bf16_t* __restrict__ xz, const float* __restrict__ cw,
    const float* __restrict__ cb, bf16_t* __restrict__ xs)
{
  int idx = blockIdx.x * 256 + threadIdx.x;
  int d4 = idx & 511;
  int l  = (idx >> 9) & 2047;
  int b  = idx >> 20;
  int d  = d4 * 4;

  float wch[4][4];
#pragma unroll
  for (int c = 0; c < 4; ++c)
#pragma unroll
    for (int k = 0; k < 4; ++k) wch[c][k] = cw[(d + c) * 4 + k];

  float acc0 = cb[d+0], acc1 = cb[d+1], acc2 = cb[d+2], acc3 = cb[d+3];
  size_t rowbase = ((size_t)b * LL + l) * 4096 + d;
#pragma unroll
  for (int k = 0; k < 4; ++k) {
    if (l - 3 + k >= 0) {
      ushort4 u = *(const ushort4*)(xz + rowbase - (size_t)(3 - k) * 4096);
      acc0 += b2f(u.x) * wch[0][k];
      acc1 += b2f(u.y) * wch[1][k];
      acc2 += b2f(u.z) * wch[2][k];
      acc3 += b2f(u.w) * wch[3][k];
    }
  }
  ushort4 o;
  float s0 = acc0 / (1.f + __expf(-acc0));
  float s1 = acc1 / (1.f + __expf(-acc1));
  float s2 = acc2 / (1.f + __expf(-acc2));
  float s3 = acc3 / (1.f + __expf(-acc3));
  o.x = f2b(s0); o.y = f2b(s1); o.z = f2b(s2); o.w = f2b(s3);
  *(ushort4*)(xs + ((size_t)b * LL + l) * (size_t)DI + d) = o;
}

// ---------------------------------------------------------------------------
// x_dbl[M,33] = xs[M,2048](bf16) @ W_x[33,2048](fp32)^T -> fp32.
// ---------------------------------------------------------------------------
__global__ __launch_bounds__(256) void xdbl_gemm(
    const bf16_t* __restrict__ xs, const float* __restrict__ W_x,
    float* __restrict__ xdbl)
{
  int row = blockIdx.x * 64 + (threadIdx.x & 63);
  int jg  = threadIdx.x >> 6;
  const bf16_t* a = xs + (size_t)row * DI;
  float acc[9];
#pragma unroll
  for (int t = 0; t < 9; ++t) acc[t] = 0.f;

  for (int d = 0; d < DI; d += 4) {
    ushort4 u = *(const ushort4*)(a + d);
    float ax = b2f(u.x), ay = b2f(u.y), az = b2f(u.z), aw = b2f(u.w);
#pragma unroll
    for (int t = 0; t < 9; ++t) {
      int j = jg + t * 4;
      if (j < 33) {
        float4 wv = *(const float4*)(W_x + (size_t)j * DI + d);
        acc[t] += ax*wv.x + ay*wv.y + az*wv.z + aw*wv.w;
      }
    }
  }
#pragma unroll
  for (int t = 0; t < 9; ++t) {
    int j = jg + t * 4;
    if (j < 33) xdbl[(size_t)row * 33 + j] = acc[t];
  }
}

// ---------------------------------------------------------------------------
// Scan pass 1: per (b,d,chunk) scan from h=0 over CLEN steps; store
// (Aprod, h_end) per state n.  states layout: [b][chunk][d][32] fp32
// (slots 0..15 = Aprod, 16..31 = h_end).
// grid: 512 blocks = b(8) x chunk(8) x dgroup(8), 256 threads.
// ---------------------------------------------------------------------------
__global__ __launch_bounds__(256) void scan_pass1(
    const float* __restrict__ xdbl, const bf16_t* __restrict__ xs,
    const float* __restrict__ W_dt, const float* __restrict__ b_dt,
    const float* __restrict__ A_log, float* __restrict__ states)
{
  const int bid = blockIdx.x;
  const int dg = bid & 7, c = (bid >> 3) & 7, b = bid >> 6;
  const int d = dg * 256 + threadIdx.x;

  float A[NST], h[NST], P[NST];
#pragma unroll
  for (int n = 0; n < NST; ++n) {
    A[n] = -__expf(A_log[(size_t)d * NST + n]);
    h[n] = 0.f; P[n] = 1.f;
  }
  const float wdt = W_dt[d], bdt = b_dt[d];

  __shared__ float sx[SUB * 33];
  const size_t rbase = (size_t)b * LL + c * CLEN;

  for (int s = 0; s < CLEN; s += SUB) {
    __syncthreads();
    for (int t = threadIdx.x; t < SUB * 33; t += 256)
      sx[t] = xdbl[(rbase + s) * 33 + t];
    __syncthreads();
#pragma unroll 4
    for (int u = 0; u < SUB; ++u) {
      float xv = b2f(xs[(rbase + s + u) * DI + d]);
      float dtr = sx[u * 33];
      float xarg = fmaf(dtr, wdt, bdt);
      float dt = (xarg > 20.f) ? xarg : log1pf(__expf(xarg));
      float dtx = dt * xv;
#pragma unroll
      for (int n = 0; n < NST; ++n) {
        float a = __expf(dt * A[n]);
        h[n] = fmaf(a, h[n], dtx * sx[u * 33 + 1 + n]);
        P[n] *= a;
      }
    }
  }
  size_t sb = (((size_t)b * NCH + c) * DI + d) * 32;
#pragma unroll
  for (int n = 0; n < NST; ++n) {
    states[sb + n]      = P[n];
    states[sb + 16 + n] = h[n];
  }
}

// ---------------------------------------------------------------------------
// Scan pass 2: compose chunk states sequentially; write h_init for each
// chunk into the Aprod slot (in place).  One thread per (b,d,n).
// ---------------------------------------------------------------------------
__global__ __launch_bounds__(256) void scan_pass2(float* __restrict__ states)
{
  int t = blockIdx.x * 256 + threadIdx.x;    // 8*2048*16 = 262144
  int n = t & 15, d = (t >> 4) & 2047, b = t >> 15;
  float h = 0.f;
  for (int c = 0; c < NCH; ++c) {
    size_t sb = (((size_t)b * NCH + c) * DI + d) * 32;
    float P  = states[sb + n];
    float h0 = states[sb + 16 + n];
    states[sb + n] = h;          // h_init entering chunk c
    h = fmaf(P, h, h0);
  }
}

// ---------------------------------------------------------------------------
// Scan pass 3: re-scan each chunk from h_init; y = C.h + D*x; gate with
// SiLU(z); write bf16 in place over xs.
// ---------------------------------------------------------------------------
__global__ __launch_bounds__(256) void scan_pass3(
    const float* __restrict__ xdbl, const bf16_t* __restrict__ xz,
    bf16_t* __restrict__ xs, const float* __restrict__ states,
    const float* __restrict__ W_dt, const float* __restrict__ b_dt,
    const float* __restrict__ A_log, const float* __restrict__ Dp)
{
  const int bid = blockIdx.x;
  const int dg = bid & 7, c = (bid >> 3) & 7, b = bid >> 6;
  const int d = dg * 256 + threadIdx.x;

  float A[NST], h[NST];
  size_t sb = (((size_t)b * NCH + c) * DI + d) * 32;
#pragma unroll
  for (int n = 0; n < NST; ++n) {
    A[n] = -__expf(A_log[(size_t)d * NST + n]);
    h[n] = states[sb + n];
  }
  const float wdt = W_dt[d], bdt = b_dt[d], Dd = Dp[d];

  __shared__ float sx[SUB * 33];
  const size_t rbase = (size_t)b * LL + c * CLEN;

  for (int s = 0; s < CLEN; s += SUB) {
    __syncthreads();
    for (int t = threadIdx.x; t < SUB * 33; t += 256)
      sx[t] = xdbl[(rbase + s) * 33 + t];
    __syncthreads();
#pragma unroll 4
    for (int u = 0; u < SUB; ++u) {
      size_t r = rbase + s + u;
      float xv = b2f(xs[r * DI + d]);
      float zv = b2f(xz[r * 4096 + DI + d]);
      float dtr = sx[u * 33];
      float xarg = fmaf(dtr, wdt, bdt);
      float dt = (xarg > 20.f) ? xarg : log1pf(__expf(xarg));
      float dtx = dt * xv;
      float y = Dd * xv;
#pragma unroll
      for (int n = 0; n < NST; ++n) {
        float a = __expf(dt * A[n]);
        h[n] = fmaf(a, h[n], dtx * sx[u * 33 + 1 + n]);
        y = fmaf(h[n], sx[u * 33 + 17 + n], y);
      }
      float sz = zv / (1.f + __expf(-zv));
      xs[r * DI + d] = f2b(y * sz);
    }
  }
}

// ---------------------------------------------------------------------------
extern "C" void kernel_launch(void* const* d_in, const int* in_sizes, int n_in,
                              void* d_out, int out_size, void* d_ws, size_t ws_size,
                              hipStream_t stream)
{
  const float* x     = (const float*)d_in[0];
  const float* W_in  = (const float*)d_in[1];
  const float* cw    = (const float*)d_in[2];
  const float* cb    = (const float*)d_in[3];
  const float* W_x   = (const float*)d_in[4];
  const float* W_dt  = (const float*)d_in[5];
  const float* b_dt  = (const float*)d_in[6];
  const float* A_log = (const float*)d_in[7];
  const float* Dp    = (const float*)d_in[8];
  const float* W_out = (const float*)d_in[9];
  float* out = (float*)d_out;

  // ws (proven 194 MB footprint): xz bf16 [16384,4096] | xs bf16 [16384,2048]
  //                               | xdbl f32 [16384,33]
  bf16_t* xz   = (bf16_t*)d_ws;
  bf16_t* xs   = xz + (size_t)MR * 4096;
  float*  xdbl = (float*)(xs + (size_t)MR * DI);

  // d_out doubles as scratch at disjoint phases:
  //   phase A (GEMM1): x_bf (33.5 MB) + Win_bf (8.4 MB)
  //   phase B (scan):  states (16.8 MB)
  //   phase C (GEMM3): final output overwrites everything
  bf16_t* x_bf   = (bf16_t*)d_out;
  bf16_t* Win_bf = x_bf + (size_t)MR * DMOD;
  float*  states = (float*)d_out;
  bf16_t* Wout_bf = xz;   // overlays dead xz after the scan

  // 0) convert GEMM1 operands to bf16 (into d_out scratch)
  cvt_bf16<<<(MR*DMOD/4 + 255)/256, 256, 0, stream>>>(x, x_bf, MR*DMOD/4);
  cvt_bf16<<<(4096*DMOD/4 + 255)/256, 256, 0, stream>>>(W_in, Win_bf, 4096*DMOD/4);
  // 1) xz = x @ W_in^T   (M=16384, N=4096, K=1024), bf16 MFMA
  mgemm_nt<bf16_t><<<dim3(4096/128, MR/128), 256, 0, stream>>>(x_bf, Win_bf, xz, 4096, DMOD);
  // 2) causal depthwise conv + bias + SiLU -> xs (bf16)
  conv_silu<<<(BB*LL*512)/256, 256, 0, stream>>>(xz, cw, cb, xs);
  // 3) x_dbl = xs @ W_x^T (M=16384, N=33, K=2048)
  xdbl_gemm<<<MR/64, 256, 0, stream>>>(xs, W_x, xdbl);
  // 4) chunked selective scan (3 passes) + D*xs + SiLU(z) gate, in place in xs
  scan_pass1<<<BB*NCH*8, 256, 0, stream>>>(xdbl, xs, W_dt, b_dt, A_log, states);
  scan_pass2<<<(BB*DI*NST)/256, 256, 0, stream>>>(states);
  scan_pass3<<<BB*NCH*8, 256, 0, stream>>>(xdbl, xz, xs, states, W_dt, b_dt, A_log, Dp);
  // 5) convert W_out -> bf16 (into dead xz region), then out = gated @ W_out^T
  cvt_bf16<<<(DMOD*DI/4 + 255)/256, 256, 0, stream>>>(W_out, Wout_bf, DMOD*DI/4);
  mgemm_nt<float><<<dim3(DMOD/128, MR/128), 256, 0, stream>>>(xs, Wout_bf, out, DMOD, DI);
}

// Round 5
// 990.359 us; speedup vs baseline: 4.7598x; 1.3821x over previous
//
#include <hip/hip_runtime.h>
#include <math.h>

// Problem constants (fixed by the reference)
#define BB    8
#define LL    2048
#define DMOD  1024
#define DI    2048
#define NST   16
#define MR    (BB*LL)   // 16384 rows
// scan chunking
#define NCH   8
#define CLEN  256       // NCH*CLEN == LL
#define SUB   64        // xdbl LDS staging granularity

typedef unsigned short bf16_t;
typedef __attribute__((ext_vector_type(8))) __bf16 bf16x8;
typedef __attribute__((ext_vector_type(4))) float  f32x4;

__device__ __forceinline__ float b2f(bf16_t u) {
  return __uint_as_float(((unsigned int)u) << 16);
}
__device__ __forceinline__ bf16_t f2b(float f) {
  unsigned int u = __float_as_uint(f);
  unsigned int r = (u + 0x7FFFu + ((u >> 16) & 1u)) >> 16;  // RNE
  return (bf16_t)r;
}

__device__ __forceinline__ void cstore(float* p, float v)  { *p = v; }
__device__ __forceinline__ void cstore(bf16_t* p, float v) { *p = f2b(v); }

// async global->LDS, 16B per lane; LDS dest = wave-uniform base + lane*16
__device__ __forceinline__ void gld16(const bf16_t* g, bf16_t* l) {
  __builtin_amdgcn_global_load_lds(
      (const __attribute__((address_space(1))) unsigned int*)g,
      (__attribute__((address_space(3))) unsigned int*)l, 16, 0, 0);
}

// ---------------------------------------------------------------------------
// fp32 -> bf16 convert (vectorized x4)
// ---------------------------------------------------------------------------
__global__ __launch_bounds__(256) void cvt_bf16(
    const float* __restrict__ in, bf16_t* __restrict__ out, int n4)
{
  int i = blockIdx.x * 256 + threadIdx.x;
  if (i >= n4) return;
  float4 v = ((const float4*)in)[i];
  ushort4 u;
  u.x = f2b(v.x); u.y = f2b(v.y); u.z = f2b(v.z); u.w = f2b(v.w);
  ((ushort4*)out)[i] = u;
}

// W_x [33,2048] fp32 -> padded bf16 [64,2048] (rows 33..63 zero)
__global__ __launch_bounds__(256) void cvt_wx(
    const float* __restrict__ W_x, bf16_t* __restrict__ Wx_bf)
{
  int i = blockIdx.x * 256 + threadIdx.x;   // 64*2048 = 131072
  int j = i >> 11;
  Wx_bf[i] = (j < 33) ? f2b(W_x[i]) : (bf16_t)0;
}

// ---------------------------------------------------------------------------
// MFMA GEMM NT: C[M,N] = A[M,K] * B[N,K]^T, bf16 inputs, fp32 acc.
// m97 structure: 128x128 tile, BK=32, 256 thr (4 waves), 4x4 16x16x32 per wave.
// grid = dim3(N/128, M/128).
// ---------------------------------------------------------------------------
template <typename TC>
__global__ __launch_bounds__(256) void mgemm_nt(
    const bf16_t* __restrict__ A, const bf16_t* __restrict__ B,
    TC* __restrict__ C, int N, int K)
{
  __shared__ __align__(16) bf16_t As[128 * 32];
  __shared__ __align__(16) bf16_t Bs[128 * 32];
  const int tid  = threadIdx.x;
  const int wave = tid >> 6;
  const int lane = tid & 63;
  const int m0 = blockIdx.y * 128;
  const int n0 = blockIdx.x * 128;
  const int wm = (wave >> 1) * 64;
  const int wn = (wave & 1) * 64;
  const int fr = lane & 15;
  const int quad = lane >> 4;

  const int srow = wave * 32 + (lane >> 2);
  const int scol = (lane & 3) * 8;                 // elements (8 bf16 = 16 B)
  const bf16_t* Ag0 = A + (size_t)(m0 + srow) * K + scol;
  const bf16_t* Ag1 = Ag0 + (size_t)16 * K;
  const bf16_t* Bg0 = B + (size_t)(n0 + srow) * K + scol;
  const bf16_t* Bg1 = Bg0 + (size_t)16 * K;
  bf16_t* lA0 = As + (wave * 32) * 32;
  bf16_t* lA1 = As + (wave * 32 + 16) * 32;
  bf16_t* lB0 = Bs + (wave * 32) * 32;
  bf16_t* lB1 = Bs + (wave * 32 + 16) * 32;

  f32x4 acc[4][4];
#pragma unroll
  for (int i = 0; i < 4; ++i)
#pragma unroll
    for (int j = 0; j < 4; ++j) acc[i][j] = (f32x4){0.f, 0.f, 0.f, 0.f};

  for (int k0 = 0; k0 < K; k0 += 32) {
    __syncthreads();
    gld16(Ag0 + k0, lA0);
    gld16(Ag1 + k0, lA1);
    gld16(Bg0 + k0, lB0);
    gld16(Bg1 + k0, lB1);
    __syncthreads();

    bf16x8 a[4], b[4];
#pragma unroll
    for (int i = 0; i < 4; ++i)
      a[i] = *(const bf16x8*)&As[(wm + i * 16 + fr) * 32 + quad * 8];
#pragma unroll
    for (int j = 0; j < 4; ++j)
      b[j] = *(const bf16x8*)&Bs[(wn + j * 16 + fr) * 32 + quad * 8];
#pragma unroll
    for (int i = 0; i < 4; ++i)
#pragma unroll
      for (int j = 0; j < 4; ++j)
        acc[i][j] = __builtin_amdgcn_mfma_f32_16x16x32_bf16(a[i], b[j], acc[i][j], 0, 0, 0);
  }

  // D col = lane&15, row = quad*4 + r  (verified m89/m91)
#pragma unroll
  for (int i = 0; i < 4; ++i)
#pragma unroll
    for (int j = 0; j < 4; ++j) {
#pragma unroll
      for (int r = 0; r < 4; ++r) {
        int grow = m0 + wm + i * 16 + quad * 4 + r;
        int gcol = n0 + wn + j * 16 + fr;
        cstore(&C[(size_t)grow * N + gcol], acc[i][j][r]);
      }
    }
}

// ---------------------------------------------------------------------------
// x_dbl MFMA GEMM: xdbl[M,33] = xs[M,2048] * Wx_bf[64,2048]^T (cols 33..47
// discarded). BM=64, BK=64, 256 thr (4 waves); wave w owns row-tile w,
// 3 col-tiles. LDS layout [kk][row][32] planes (kk = K sub-step).
// grid = MR/64 = 256 blocks.
// ---------------------------------------------------------------------------
__global__ __launch_bounds__(256) void xdbl_mfma(
    const bf16_t* __restrict__ xs, const bf16_t* __restrict__ Wx_bf,
    float* __restrict__ xdbl)
{
  __shared__ __align__(16) bf16_t As[2 * 64 * 32];   // 8 KB
  __shared__ __align__(16) bf16_t Bs[2 * 64 * 32];   // 8 KB
  const int tid  = threadIdx.x;
  const int wave = tid >> 6;
  const int lane = tid & 63;
  const int m0 = blockIdx.x * 64;
  const int fr = lane & 15;
  const int quad = lane >> 4;

  // staging: lane covers row wave*16 + (lane>>2), cols (lane&3)*8 .. +8
  const int srow = wave * 16 + (lane >> 2);
  const int scol = (lane & 3) * 8;
  const bf16_t* Ag = xs + (size_t)(m0 + srow) * DI + scol;
  const bf16_t* Bg = Wx_bf + (size_t)srow * DI + scol;
  bf16_t* lA = As + wave * 512;   // + kk*2048
  bf16_t* lB = Bs + wave * 512;

  f32x4 acc[3];
#pragma unroll
  for (int jt = 0; jt < 3; ++jt) acc[jt] = (f32x4){0.f, 0.f, 0.f, 0.f};

  for (int k0 = 0; k0 < DI; k0 += 64) {
    __syncthreads();
#pragma unroll
    for (int kk = 0; kk < 2; ++kk) {
      gld16(Ag + k0 + kk * 32, lA + kk * 2048);
      gld16(Bg + k0 + kk * 32, lB + kk * 2048);
    }
    __syncthreads();

#pragma unroll
    for (int kk = 0; kk < 2; ++kk) {
      bf16x8 a = *(const bf16x8*)&As[kk * 2048 + (wave * 16 + fr) * 32 + quad * 8];
#pragma unroll
      for (int jt = 0; jt < 3; ++jt) {
        bf16x8 b = *(const bf16x8*)&Bs[kk * 2048 + (jt * 16 + fr) * 32 + quad * 8];
        acc[jt] = __builtin_amdgcn_mfma_f32_16x16x32_bf16(a, b, acc[jt], 0, 0, 0);
      }
    }
  }

#pragma unroll
  for (int jt = 0; jt < 3; ++jt) {
#pragma unroll
    for (int r = 0; r < 4; ++r) {
      int grow = m0 + wave * 16 + quad * 4 + r;
      int j = jt * 16 + fr;
      if (j < 33) xdbl[(size_t)grow * 33 + j] = acc[jt][r];
    }
  }
}

// ---------------------------------------------------------------------------
// Causal depthwise conv1d (k=4) + bias + SiLU.  bf16 xz -> bf16 xs.
// ---------------------------------------------------------------------------
__global__ __launch_bounds__(256) void conv_silu(
    const bf16_t* __restrict__ xz, const float* __restrict__ cw,
    const float* __restrict__ cb, bf16_t* __restrict__ xs)
{
  int idx = blockIdx.x * 256 + threadIdx.x;
  int d4 = idx & 511;
  int l  = (idx >> 9) & 2047;
  int b  = idx >> 20;
  int d  = d4 * 4;

  float wch[4][4];
#pragma unroll
  for (int c = 0; c < 4; ++c)
#pragma unroll
    for (int k = 0; k < 4; ++k) wch[c][k] = cw[(d + c) * 4 + k];

  float acc0 = cb[d+0], acc1 = cb[d+1], acc2 = cb[d+2], acc3 = cb[d+3];
  size_t rowbase = ((size_t)b * LL + l) * 4096 + d;
#pragma unroll
  for (int k = 0; k < 4; ++k) {
    if (l - 3 + k >= 0) {
      ushort4 u = *(const ushort4*)(xz + rowbase - (size_t)(3 - k) * 4096);
      acc0 += b2f(u.x) * wch[0][k];
      acc1 += b2f(u.y) * wch[1][k];
      acc2 += b2f(u.z) * wch[2][k];
      acc3 += b2f(u.w) * wch[3][k];
    }
  }
  ushort4 o;
  float s0 = acc0 / (1.f + __expf(-acc0));
  float s1 = acc1 / (1.f + __expf(-acc1));
  float s2 = acc2 / (1.f + __expf(-acc2));
  float s3 = acc3 / (1.f + __expf(-acc3));
  o.x = f2b(s0); o.y = f2b(s1); o.z = f2b(s2); o.w = f2b(s3);
  *(ushort4*)(xs + ((size_t)b * LL + l) * (size_t)DI + d) = o;
}

// ---------------------------------------------------------------------------
// Scan pass 1: per (b,d,chunk) scan from h=0 over CLEN steps; store
// (Aprod, h_end).  states: [b][chunk][d][32] fp32 (0..15 Aprod, 16..31 h_end).
// ---------------------------------------------------------------------------
__global__ __launch_bounds__(256) void scan_pass1(
    const float* __restrict__ xdbl, const bf16_t* __restrict__ xs,
    const float* __restrict__ W_dt, const float* __restrict__ b_dt,
    const float* __restrict__ A_log, float* __restrict__ states)
{
  const int bid = blockIdx.x;
  const int dg = bid & 7, c = (bid >> 3) & 7, b = bid >> 6;
  const int d = dg * 256 + threadIdx.x;

  float A[NST], h[NST], P[NST];
#pragma unroll
  for (int n = 0; n < NST; ++n) {
    A[n] = -__expf(A_log[(size_t)d * NST + n]);
    h[n] = 0.f; P[n] = 1.f;
  }
  const float wdt = W_dt[d], bdt = b_dt[d];

  __shared__ float sx[SUB * 33];
  const size_t rbase = (size_t)b * LL + c * CLEN;

  for (int s = 0; s < CLEN; s += SUB) {
    __syncthreads();
    for (int t = threadIdx.x; t < SUB * 33; t += 256)
      sx[t] = xdbl[(rbase + s) * 33 + t];
    __syncthreads();
#pragma unroll 4
    for (int u = 0; u < SUB; ++u) {
      float xv = b2f(xs[(rbase + s + u) * DI + d]);
      float dtr = sx[u * 33];
      float xarg = fmaf(dtr, wdt, bdt);
      float dt = (xarg > 20.f) ? xarg : log1pf(__expf(xarg));
      float dtx = dt * xv;
#pragma unroll
      for (int n = 0; n < NST; ++n) {
        float a = __expf(dt * A[n]);
        h[n] = fmaf(a, h[n], dtx * sx[u * 33 + 1 + n]);
        P[n] *= a;
      }
    }
  }
  size_t sb = (((size_t)b * NCH + c) * DI + d) * 32;
#pragma unroll
  for (int n = 0; n < NST; ++n) {
    states[sb + n]      = P[n];
    states[sb + 16 + n] = h[n];
  }
}

// ---------------------------------------------------------------------------
// Scan pass 2: compose chunk states sequentially; h_init -> Aprod slot.
// ---------------------------------------------------------------------------
__global__ __launch_bounds__(256) void scan_pass2(float* __restrict__ states)
{
  int t = blockIdx.x * 256 + threadIdx.x;    // 8*2048*16 = 262144
  int n = t & 15, d = (t >> 4) & 2047, b = t >> 15;
  float h = 0.f;
  for (int c = 0; c < NCH; ++c) {
    size_t sb = (((size_t)b * NCH + c) * DI + d) * 32;
    float P  = states[sb + n];
    float h0 = states[sb + 16 + n];
    states[sb + n] = h;          // h_init entering chunk c
    h = fmaf(P, h, h0);
  }
}

// ---------------------------------------------------------------------------
// Scan pass 3: re-scan from h_init; y = C.h + D*x; gate SiLU(z); bf16 in place.
// ---------------------------------------------------------------------------
__global__ __launch_bounds__(256) void scan_pass3(
    const float* __restrict__ xdbl, const bf16_t* __restrict__ xz,
    bf16_t* __restrict__ xs, const float* __restrict__ states,
    const float* __restrict__ W_dt, const float* __restrict__ b_dt,
    const float* __restrict__ A_log, const float* __restrict__ Dp)
{
  const int bid = blockIdx.x;
  const int dg = bid & 7, c = (bid >> 3) & 7, b = bid >> 6;
  const int d = dg * 256 + threadIdx.x;

  float A[NST], h[NST];
  size_t sb = (((size_t)b * NCH + c) * DI + d) * 32;
#pragma unroll
  for (int n = 0; n < NST; ++n) {
    A[n] = -__expf(A_log[(size_t)d * NST + n]);
    h[n] = states[sb + n];
  }
  const float wdt = W_dt[d], bdt = b_dt[d], Dd = Dp[d];

  __shared__ float sx[SUB * 33];
  const size_t rbase = (size_t)b * LL + c * CLEN;

  for (int s = 0; s < CLEN; s += SUB) {
    __syncthreads();
    for (int t = threadIdx.x; t < SUB * 33; t += 256)
      sx[t] = xdbl[(rbase + s) * 33 + t];
    __syncthreads();
#pragma unroll 4
    for (int u = 0; u < SUB; ++u) {
      size_t r = rbase + s + u;
      float xv = b2f(xs[r * DI + d]);
      float zv = b2f(xz[r * 4096 + DI + d]);
      float dtr = sx[u * 33];
      float xarg = fmaf(dtr, wdt, bdt);
      float dt = (xarg > 20.f) ? xarg : log1pf(__expf(xarg));
      float dtx = dt * xv;
      float y = Dd * xv;
#pragma unroll
      for (int n = 0; n < NST; ++n) {
        float a = __expf(dt * A[n]);
        h[n] = fmaf(a, h[n], dtx * sx[u * 33 + 1 + n]);
        y = fmaf(h[n], sx[u * 33 + 17 + n], y);
      }
      float sz = zv / (1.f + __expf(-zv));
      xs[r * DI + d] = f2b(y * sz);
    }
  }
}

// ---------------------------------------------------------------------------
extern "C" void kernel_launch(void* const* d_in, const int* in_sizes, int n_in,
                              void* d_out, int out_size, void* d_ws, size_t ws_size,
                              hipStream_t stream)
{
  const float* x     = (const float*)d_in[0];
  const float* W_in  = (const float*)d_in[1];
  const float* cw    = (const float*)d_in[2];
  const float* cb    = (const float*)d_in[3];
  const float* W_x   = (const float*)d_in[4];
  const float* W_dt  = (const float*)d_in[5];
  const float* b_dt  = (const float*)d_in[6];
  const float* A_log = (const float*)d_in[7];
  const float* Dp    = (const float*)d_in[8];
  const float* W_out = (const float*)d_in[9];
  float* out = (float*)d_out;

  // ws (proven 194 MB): xz bf16 [16384,4096] | xs bf16 [16384,2048] | xdbl f32 [16384,33]
  bf16_t* xz   = (bf16_t*)d_ws;
  bf16_t* xs   = xz + (size_t)MR * 4096;
  float*  xdbl = (float*)(xs + (size_t)MR * DI);

  // d_out as phase-disjoint scratch (64 MB):
  //   [0,32M)   x_bf      (dead after GEMM1)
  //   [32M,40M) Win_bf    (dead after GEMM1)
  //   [40M,40.25M) Wx_bf  (dead after xdbl_mfma)
  //   [0,16.8M) states    (scan phase only)
  //   final GEMM3 overwrites all of d_out
  bf16_t* x_bf    = (bf16_t*)d_out;
  bf16_t* Win_bf  = x_bf + (size_t)MR * DMOD;
  bf16_t* Wx_bf   = Win_bf + (size_t)4096 * DMOD;
  float*  states  = (float*)d_out;
  bf16_t* Wout_bf = xz;   // overlays dead xz after scan pass 3

  // 0) operand conversions
  cvt_bf16<<<(MR*DMOD/4 + 255)/256, 256, 0, stream>>>(x, x_bf, MR*DMOD/4);
  cvt_bf16<<<(4096*DMOD/4 + 255)/256, 256, 0, stream>>>(W_in, Win_bf, 4096*DMOD/4);
  cvt_wx<<<(64*DI)/256, 256, 0, stream>>>(W_x, Wx_bf);
  // 1) xz = x @ W_in^T   (M=16384, N=4096, K=1024) bf16 MFMA
  mgemm_nt<bf16_t><<<dim3(4096/128, MR/128), 256, 0, stream>>>(x_bf, Win_bf, xz, 4096, DMOD);
  // 2) causal depthwise conv + bias + SiLU -> xs (bf16)
  conv_silu<<<(BB*LL*512)/256, 256, 0, stream>>>(xz, cw, cb, xs);
  // 3) x_dbl = xs @ W_x^T (MFMA, N padded to 48)
  xdbl_mfma<<<MR/64, 256, 0, stream>>>(xs, Wx_bf, xdbl);
  // 4) chunked selective scan (3 passes) + D*xs + SiLU(z) gate, in place in xs
  scan_pass1<<<BB*NCH*8, 256, 0, stream>>>(xdbl, xs, W_dt, b_dt, A_log, states);
  scan_pass2<<<(BB*DI*NST)/256, 256, 0, stream>>>(states);
  scan_pass3<<<BB*NCH*8, 256, 0, stream>>>(xdbl, xz, xs, states, W_dt, b_dt, A_log, Dp);
  // 5) W_out -> bf16 (dead xz region), then out = gated @ W_out^T
  cvt_bf16<<<(DMOD*DI/4 + 255)/256, 256, 0, stream>>>(W_out, Wout_bf, DMOD*DI/4);
  mgemm_nt<float><<<dim3(DMOD/128, MR/128), 256, 0, stream>>>(xs, Wout_bf, out, DMOD, DI);
}

// Round 6
// 951.494 us; speedup vs baseline: 4.9542x; 1.0408x over previous
//
#include <hip/hip_runtime.h>
#include <math.h>

// Problem constants (fixed by the reference)
#define BB    8
#define LL    2048
#define DMOD  1024
#define DI    2048
#define NST   16
#define MR    (BB*LL)   // 16384 rows
// scan chunking
#define NCH   16
#define CLEN  128       // NCH*CLEN == LL
#define XDW   36        // padded xdbl row: [dt, pad,pad,pad, B0..15, C0..15]

typedef unsigned short bf16_t;
typedef __attribute__((ext_vector_type(8))) __bf16 bf16x8;
typedef __attribute__((ext_vector_type(4))) float  f32x4;

__device__ __forceinline__ float b2f(bf16_t u) {
  return __uint_as_float(((unsigned int)u) << 16);
}
__device__ __forceinline__ bf16_t f2b(float f) {
  unsigned int u = __float_as_uint(f);
  unsigned int r = (u + 0x7FFFu + ((u >> 16) & 1u)) >> 16;  // RNE
  return (bf16_t)r;
}

__device__ __forceinline__ void cstore(float* p, float v)  { *p = v; }
__device__ __forceinline__ void cstore(bf16_t* p, float v) { *p = f2b(v); }

// async global->LDS, 16B per lane; LDS dest = wave-uniform base + lane*16
__device__ __forceinline__ void gld16(const bf16_t* g, bf16_t* l) {
  __builtin_amdgcn_global_load_lds(
      (const __attribute__((address_space(1))) unsigned int*)g,
      (__attribute__((address_space(3))) unsigned int*)l, 16, 0, 0);
}

// softplus via 2 HW transcendentals (abs err ~1e-7, fine vs 5.5e-4 budget)
__device__ __forceinline__ float softplus(float x) {
  return (x > 20.f) ? x : __logf(1.f + __expf(x));
}
__device__ __forceinline__ float silu(float z) {
  return z * __builtin_amdgcn_rcpf(1.f + __expf(-z));
}

// ---------------------------------------------------------------------------
// fp32 -> bf16 convert (vectorized x4)
// ---------------------------------------------------------------------------
__global__ __launch_bounds__(256) void cvt_bf16(
    const float* __restrict__ in, bf16_t* __restrict__ out, int n4)
{
  int i = blockIdx.x * 256 + threadIdx.x;
  if (i >= n4) return;
  float4 v = ((const float4*)in)[i];
  ushort4 u;
  u.x = f2b(v.x); u.y = f2b(v.y); u.z = f2b(v.z); u.w = f2b(v.w);
  ((ushort4*)out)[i] = u;
}

// W_x [33,2048] fp32 -> padded bf16 [64,2048] (rows 33..63 zero)
__global__ __launch_bounds__(256) void cvt_wx(
    const float* __restrict__ W_x, bf16_t* __restrict__ Wx_bf)
{
  int i = blockIdx.x * 256 + threadIdx.x;   // 64*2048 = 131072
  int j = i >> 11;
  Wx_bf[i] = (j < 33) ? f2b(W_x[i]) : (bf16_t)0;
}

// ---------------------------------------------------------------------------
// MFMA GEMM NT: C[M,N] = A[M,K] * B[N,K]^T, bf16 inputs, fp32 acc.
// 128x128 tile, BK=32, 256 thr (4 waves), 4x4 16x16x32 per wave.
// ---------------------------------------------------------------------------
template <typename TC>
__global__ __launch_bounds__(256) void mgemm_nt(
    const bf16_t* __restrict__ A, const bf16_t* __restrict__ B,
    TC* __restrict__ C, int N, int K)
{
  __shared__ __align__(16) bf16_t As[128 * 32];
  __shared__ __align__(16) bf16_t Bs[128 * 32];
  const int tid  = threadIdx.x;
  const int wave = tid >> 6;
  const int lane = tid & 63;
  const int m0 = blockIdx.y * 128;
  const int n0 = blockIdx.x * 128;
  const int wm = (wave >> 1) * 64;
  const int wn = (wave & 1) * 64;
  const int fr = lane & 15;
  const int quad = lane >> 4;

  const int srow = wave * 32 + (lane >> 2);
  const int scol = (lane & 3) * 8;
  const bf16_t* Ag0 = A + (size_t)(m0 + srow) * K + scol;
  const bf16_t* Ag1 = Ag0 + (size_t)16 * K;
  const bf16_t* Bg0 = B + (size_t)(n0 + srow) * K + scol;
  const bf16_t* Bg1 = Bg0 + (size_t)16 * K;
  bf16_t* lA0 = As + (wave * 32) * 32;
  bf16_t* lA1 = As + (wave * 32 + 16) * 32;
  bf16_t* lB0 = Bs + (wave * 32) * 32;
  bf16_t* lB1 = Bs + (wave * 32 + 16) * 32;

  f32x4 acc[4][4];
#pragma unroll
  for (int i = 0; i < 4; ++i)
#pragma unroll
    for (int j = 0; j < 4; ++j) acc[i][j] = (f32x4){0.f, 0.f, 0.f, 0.f};

  for (int k0 = 0; k0 < K; k0 += 32) {
    __syncthreads();
    gld16(Ag0 + k0, lA0);
    gld16(Ag1 + k0, lA1);
    gld16(Bg0 + k0, lB0);
    gld16(Bg1 + k0, lB1);
    __syncthreads();

    bf16x8 a[4], b[4];
#pragma unroll
    for (int i = 0; i < 4; ++i)
      a[i] = *(const bf16x8*)&As[(wm + i * 16 + fr) * 32 + quad * 8];
#pragma unroll
    for (int j = 0; j < 4; ++j)
      b[j] = *(const bf16x8*)&Bs[(wn + j * 16 + fr) * 32 + quad * 8];
#pragma unroll
    for (int i = 0; i < 4; ++i)
#pragma unroll
      for (int j = 0; j < 4; ++j)
        acc[i][j] = __builtin_amdgcn_mfma_f32_16x16x32_bf16(a[i], b[j], acc[i][j], 0, 0, 0);
  }

  // D col = lane&15, row = quad*4 + r
#pragma unroll
  for (int i = 0; i < 4; ++i)
#pragma unroll
    for (int j = 0; j < 4; ++j) {
#pragma unroll
      for (int r = 0; r < 4; ++r) {
        int grow = m0 + wm + i * 16 + quad * 4 + r;
        int gcol = n0 + wn + j * 16 + fr;
        cstore(&C[(size_t)grow * N + gcol], acc[i][j][r]);
      }
    }
}

// ---------------------------------------------------------------------------
// x_dbl MFMA GEMM: xdbl[M,36pad] = xs[M,2048] * Wx_bf[64,2048]^T.
// BM=64, BK=64, 4 waves; wave w owns row-tile w, 3 col-tiles. grid = MR/64.
// Output row layout: dt at col 0, B at 4..19, C at 20..35.
// ---------------------------------------------------------------------------
__global__ __launch_bounds__(256) void xdbl_mfma(
    const bf16_t* __restrict__ xs, const bf16_t* __restrict__ Wx_bf,
    float* __restrict__ xdbl)
{
  __shared__ __align__(16) bf16_t As[2 * 64 * 32];
  __shared__ __align__(16) bf16_t Bs[2 * 64 * 32];
  const int tid  = threadIdx.x;
  const int wave = tid >> 6;
  const int lane = tid & 63;
  const int m0 = blockIdx.x * 64;
  const int fr = lane & 15;
  const int quad = lane >> 4;

  const int srow = wave * 16 + (lane >> 2);
  const int scol = (lane & 3) * 8;
  const bf16_t* Ag = xs + (size_t)(m0 + srow) * DI + scol;
  const bf16_t* Bg = Wx_bf + (size_t)srow * DI + scol;
  bf16_t* lA = As + wave * 512;
  bf16_t* lB = Bs + wave * 512;

  f32x4 acc[3];
#pragma unroll
  for (int jt = 0; jt < 3; ++jt) acc[jt] = (f32x4){0.f, 0.f, 0.f, 0.f};

  for (int k0 = 0; k0 < DI; k0 += 64) {
    __syncthreads();
#pragma unroll
    for (int kk = 0; kk < 2; ++kk) {
      gld16(Ag + k0 + kk * 32, lA + kk * 2048);
      gld16(Bg + k0 + kk * 32, lB + kk * 2048);
    }
    __syncthreads();

#pragma unroll
    for (int kk = 0; kk < 2; ++kk) {
      bf16x8 a = *(const bf16x8*)&As[kk * 2048 + (wave * 16 + fr) * 32 + quad * 8];
#pragma unroll
      for (int jt = 0; jt < 3; ++jt) {
        bf16x8 b = *(const bf16x8*)&Bs[kk * 2048 + (jt * 16 + fr) * 32 + quad * 8];
        acc[jt] = __builtin_amdgcn_mfma_f32_16x16x32_bf16(a, b, acc[jt], 0, 0, 0);
      }
    }
  }

#pragma unroll
  for (int jt = 0; jt < 3; ++jt) {
#pragma unroll
    for (int r = 0; r < 4; ++r) {
      int grow = m0 + wave * 16 + quad * 4 + r;
      int j = jt * 16 + fr;
      if (j < 33) {
        int col = (j == 0) ? 0 : (j + 3);
        xdbl[(size_t)grow * XDW + col] = acc[jt][r];
      }
    }
  }
}

// ---------------------------------------------------------------------------
// Causal depthwise conv1d (k=4) + bias + SiLU.  bf16 xz -> bf16 xs.
// ---------------------------------------------------------------------------
__global__ __launch_bounds__(256) void conv_silu(
    const bf16_t* __restrict__ xz, const float* __restrict__ cw,
    const float* __restrict__ cb, bf16_t* __restrict__ xs)
{
  int idx = blockIdx.x * 256 + threadIdx.x;
  int d4 = idx & 511;
  int l  = (idx >> 9) & 2047;
  int b  = idx >> 20;
  int d  = d4 * 4;

  float wch[4][4];
#pragma unroll
  for (int c = 0; c < 4; ++c)
#pragma unroll
    for (int k = 0; k < 4; ++k) wch[c][k] = cw[(d + c) * 4 + k];

  float acc0 = cb[d+0], acc1 = cb[d+1], acc2 = cb[d+2], acc3 = cb[d+3];
  size_t rowbase = ((size_t)b * LL + l) * 4096 + d;
#pragma unroll
  for (int k = 0; k < 4; ++k) {
    if (l - 3 + k >= 0) {
      ushort4 u = *(const ushort4*)(xz + rowbase - (size_t)(3 - k) * 4096);
      acc0 += b2f(u.x) * wch[0][k];
      acc1 += b2f(u.y) * wch[1][k];
      acc2 += b2f(u.z) * wch[2][k];
      acc3 += b2f(u.w) * wch[3][k];
    }
  }
  ushort4 o;
  o.x = f2b(silu(acc0)); o.y = f2b(silu(acc1));
  o.z = f2b(silu(acc2)); o.w = f2b(silu(acc3));
  *(ushort4*)(xs + ((size_t)b * LL + l) * (size_t)DI + d) = o;
}

// ---------------------------------------------------------------------------
// Scan pass 1: per (b, chunk) scan from h=0; 2 channels per thread.
// grid: 512 = b(8) x chunk(16) x dgroup(4); thread covers d0=dg*512+tid,
// d1=d0+256.  P[n] computed as exp2(A2[n]*sum(dt)) -- no per-step product.
// states: [b][c][d][32] fp32 (0..15 P, 16..31 h_end).
// ---------------------------------------------------------------------------
__global__ __launch_bounds__(256) void scan_pass1(
    const float* __restrict__ xdbl, const bf16_t* __restrict__ xs,
    const float* __restrict__ W_dt, const float* __restrict__ b_dt,
    const float* __restrict__ A_log, float* __restrict__ states)
{
  const int bid = blockIdx.x;
  const int dg = bid & 3, c = (bid >> 2) & 15, b = bid >> 6;
  const int d0 = dg * 512 + threadIdx.x;
  const int d1 = d0 + 256;

  float A2a[NST], A2b[NST], ha[NST], hb[NST];
#pragma unroll
  for (int n = 0; n < NST; ++n) {
    A2a[n] = -__expf(A_log[(size_t)d0 * NST + n]) * 1.44269504f;
    A2b[n] = -__expf(A_log[(size_t)d1 * NST + n]) * 1.44269504f;
    ha[n] = 0.f; hb[n] = 0.f;
  }
  const float wdt0 = W_dt[d0], bdt0 = b_dt[d0];
  const float wdt1 = W_dt[d1], bdt1 = b_dt[d1];
  float dts0 = 0.f, dts1 = 0.f;

  __shared__ float sx[64 * XDW];
  const size_t rbase = (size_t)b * LL + c * CLEN;

  float xv0 = b2f(xs[rbase * DI + d0]);
  float xv1 = b2f(xs[rbase * DI + d1]);

  for (int s = 0; s < CLEN; s += 64) {
    __syncthreads();
    const float* xg = xdbl + (rbase + s) * XDW;
    for (int q = threadIdx.x; q < 64 * XDW; q += 256) sx[q] = xg[q];
    __syncthreads();
#pragma unroll 2
    for (int u = 0; u < 64; ++u) {
      int tn = s + u + 1;
      float nx0 = 0.f, nx1 = 0.f;
      if (tn < CLEN) {
        nx0 = b2f(xs[(rbase + tn) * DI + d0]);
        nx1 = b2f(xs[(rbase + tn) * DI + d1]);
      }
      float dtr = sx[u * XDW];
      float dt0 = softplus(fmaf(dtr, wdt0, bdt0));
      float dt1 = softplus(fmaf(dtr, wdt1, bdt1));
      dts0 += dt0; dts1 += dt1;
      float dx0 = dt0 * xv0, dx1 = dt1 * xv1;
      const float4* Bp = (const float4*)&sx[u * XDW + 4];
#pragma unroll
      for (int n4 = 0; n4 < 4; ++n4) {
        float4 Bv = Bp[n4];
        float bb[4] = {Bv.x, Bv.y, Bv.z, Bv.w};
#pragma unroll
        for (int k = 0; k < 4; ++k) {
          int n = n4 * 4 + k;
          ha[n] = fmaf(exp2f(dt0 * A2a[n]), ha[n], dx0 * bb[k]);
          hb[n] = fmaf(exp2f(dt1 * A2b[n]), hb[n], dx1 * bb[k]);
        }
      }
      xv0 = nx0; xv1 = nx1;
    }
  }
  size_t sb0 = (((size_t)b * NCH + c) * DI + d0) * 32;
  size_t sb1 = (((size_t)b * NCH + c) * DI + d1) * 32;
#pragma unroll
  for (int n = 0; n < NST; ++n) {
    states[sb0 + n]      = exp2f(dts0 * A2a[n]);
    states[sb0 + 16 + n] = ha[n];
    states[sb1 + n]      = exp2f(dts1 * A2b[n]);
    states[sb1 + 16 + n] = hb[n];
  }
}

// ---------------------------------------------------------------------------
// Scan pass 2: compose chunk states sequentially; h_init -> P slot (in place).
// ---------------------------------------------------------------------------
__global__ __launch_bounds__(256) void scan_pass2(float* __restrict__ states)
{
  int t = blockIdx.x * 256 + threadIdx.x;    // 8*2048*16 = 262144
  int n = t & 15, d = (t >> 4) & 2047, b = t >> 15;
  float h = 0.f;
  for (int c = 0; c < NCH; ++c) {
    size_t sb = (((size_t)b * NCH + c) * DI + d) * 32;
    float P  = states[sb + n];
    float h0 = states[sb + 16 + n];
    states[sb + n] = h;          // h_init entering chunk c
    h = fmaf(P, h, h0);
  }
}

// ---------------------------------------------------------------------------
// Scan pass 3: re-scan from h_init; y = C.h + D*x; gate SiLU(z); bf16 in place.
// Same decomposition as pass 1.
// ---------------------------------------------------------------------------
__global__ __launch_bounds__(256) void scan_pass3(
    const float* __restrict__ xdbl, const bf16_t* __restrict__ xz,
    bf16_t* __restrict__ xs, const float* __restrict__ states,
    const float* __restrict__ W_dt, const float* __restrict__ b_dt,
    const float* __restrict__ A_log, const float* __restrict__ Dp)
{
  const int bid = blockIdx.x;
  const int dg = bid & 3, c = (bid >> 2) & 15, b = bid >> 6;
  const int d0 = dg * 512 + threadIdx.x;
  const int d1 = d0 + 256;

  float A2a[NST], A2b[NST], ha[NST], hb[NST];
  size_t sb0 = (((size_t)b * NCH + c) * DI + d0) * 32;
  size_t sb1 = (((size_t)b * NCH + c) * DI + d1) * 32;
#pragma unroll
  for (int n = 0; n < NST; ++n) {
    A2a[n] = -__expf(A_log[(size_t)d0 * NST + n]) * 1.44269504f;
    A2b[n] = -__expf(A_log[(size_t)d1 * NST + n]) * 1.44269504f;
    ha[n] = states[sb0 + n];
    hb[n] = states[sb1 + n];
  }
  const float wdt0 = W_dt[d0], bdt0 = b_dt[d0];
  const float wdt1 = W_dt[d1], bdt1 = b_dt[d1];
  const float Dd0 = Dp[d0], Dd1 = Dp[d1];

  __shared__ float sx[64 * XDW];
  const size_t rbase = (size_t)b * LL + c * CLEN;

  float xv0 = b2f(xs[rbase * DI + d0]);
  float xv1 = b2f(xs[rbase * DI + d1]);
  float zv0 = b2f(xz[rbase * 4096 + DI + d0]);
  float zv1 = b2f(xz[rbase * 4096 + DI + d1]);

  for (int s = 0; s < CLEN; s += 64) {
    __syncthreads();
    const float* xg = xdbl + (rbase + s) * XDW;
    for (int q = threadIdx.x; q < 64 * XDW; q += 256) sx[q] = xg[q];
    __syncthreads();
#pragma unroll 2
    for (int u = 0; u < 64; ++u) {
      size_t r = rbase + s + u;
      int tn = s + u + 1;
      float nx0 = 0.f, nx1 = 0.f, nz0 = 0.f, nz1 = 0.f;
      if (tn < CLEN) {
        nx0 = b2f(xs[(rbase + tn) * DI + d0]);
        nx1 = b2f(xs[(rbase + tn) * DI + d1]);
        nz0 = b2f(xz[(rbase + tn) * 4096 + DI + d0]);
        nz1 = b2f(xz[(rbase + tn) * 4096 + DI + d1]);
      }
      float dtr = sx[u * XDW];
      float dt0 = softplus(fmaf(dtr, wdt0, bdt0));
      float dt1 = softplus(fmaf(dtr, wdt1, bdt1));
      float dx0 = dt0 * xv0, dx1 = dt1 * xv1;
      float y0 = Dd0 * xv0, y1 = Dd1 * xv1;
      const float4* Bp = (const float4*)&sx[u * XDW + 4];
      const float4* Cp = (const float4*)&sx[u * XDW + 20];
#pragma unroll
      for (int n4 = 0; n4 < 4; ++n4) {
        float4 Bv = Bp[n4];
        float4 Cv = Cp[n4];
        float bb[4] = {Bv.x, Bv.y, Bv.z, Bv.w};
        float cc[4] = {Cv.x, Cv.y, Cv.z, Cv.w};
#pragma unroll
        for (int k = 0; k < 4; ++k) {
          int n = n4 * 4 + k;
          ha[n] = fmaf(exp2f(dt0 * A2a[n]), ha[n], dx0 * bb[k]);
          hb[n] = fmaf(exp2f(dt1 * A2b[n]), hb[n], dx1 * bb[k]);
          y0 = fmaf(ha[n], cc[k], y0);
          y1 = fmaf(hb[n], cc[k], y1);
        }
      }
      xs[r * DI + d0] = f2b(y0 * silu(zv0));
      xs[r * DI + d1] = f2b(y1 * silu(zv1));
      xv0 = nx0; xv1 = nx1; zv0 = nz0; zv1 = nz1;
    }
  }
}

// ---------------------------------------------------------------------------
extern "C" void kernel_launch(void* const* d_in, const int* in_sizes, int n_in,
                              void* d_out, int out_size, void* d_ws, size_t ws_size,
                              hipStream_t stream)
{
  const float* x     = (const float*)d_in[0];
  const float* W_in  = (const float*)d_in[1];
  const float* cw    = (const float*)d_in[2];
  const float* cb    = (const float*)d_in[3];
  const float* W_x   = (const float*)d_in[4];
  const float* W_dt  = (const float*)d_in[5];
  const float* b_dt  = (const float*)d_in[6];
  const float* A_log = (const float*)d_in[7];
  const float* Dp    = (const float*)d_in[8];
  const float* W_out = (const float*)d_in[9];
  float* out = (float*)d_out;

  // ws (proven-safe footprint): xz bf16 [16384,4096] | xs bf16 [16384,2048]
  bf16_t* xz = (bf16_t*)d_ws;
  bf16_t* xs = xz + (size_t)MR * 4096;

  // d_out (64 MiB fp32) as phase-disjoint scratch:
  //   conversions: x_bf [0,32M) | Win_bf [32M,40M) | Wx_bf [40M,40.25M)
  //   scan:        states [0,33.6M) | xdbl [33.6M,36M)  (x_bf/Win_bf dead)
  //   GEMM3 output overwrites everything last.
  bf16_t* x_bf    = (bf16_t*)d_out;
  bf16_t* Win_bf  = x_bf + (size_t)MR * DMOD;
  bf16_t* Wx_bf   = Win_bf + (size_t)4096 * DMOD;
  float*  states  = (float*)d_out;
  float*  xdbl    = states + (size_t)BB * NCH * DI * 32;   // 8.39M floats in
  bf16_t* Wout_bf = xz;   // overlays dead xz after scan pass 3

  // 0) operand conversions
  cvt_bf16<<<(MR*DMOD/4 + 255)/256, 256, 0, stream>>>(x, x_bf, MR*DMOD/4);
  cvt_bf16<<<(4096*DMOD/4 + 255)/256, 256, 0, stream>>>(W_in, Win_bf, 4096*DMOD/4);
  cvt_wx<<<(64*DI)/256, 256, 0, stream>>>(W_x, Wx_bf);
  // 1) xz = x @ W_in^T   (M=16384, N=4096, K=1024) bf16 MFMA
  mgemm_nt<bf16_t><<<dim3(4096/128, MR/128), 256, 0, stream>>>(x_bf, Win_bf, xz, 4096, DMOD);
  // 2) causal depthwise conv + bias + SiLU -> xs (bf16)
  conv_silu<<<(BB*LL*512)/256, 256, 0, stream>>>(xz, cw, cb, xs);
  // 3) x_dbl (padded rows) = xs @ W_x^T (MFMA)
  xdbl_mfma<<<MR/64, 256, 0, stream>>>(xs, Wx_bf, xdbl);
  // 4) chunked selective scan (3 passes) + D*xs + SiLU(z) gate, in place in xs
  scan_pass1<<<BB*NCH*4, 256, 0, stream>>>(xdbl, xs, W_dt, b_dt, A_log, states);
  scan_pass2<<<(BB*DI*NST)/256, 256, 0, stream>>>(states);
  scan_pass3<<<BB*NCH*4, 256, 0, stream>>>(xdbl, xz, xs, states, W_dt, b_dt, A_log, Dp);
  // 5) W_out -> bf16 (dead xz region), then out = gated @ W_out^T
  cvt_bf16<<<(DMOD*DI/4 + 255)/256, 256, 0, stream>>>(W_out, Wout_bf, DMOD*DI/4);
  mgemm_nt<float><<<dim3(DMOD/128, MR/128), 256, 0, stream>>>(xs, Wout_bf, out, DMOD, DI);
}